// Round 1
// baseline (677.773 us; speedup 1.0000x reference)
//
#include <hip/hip_runtime.h>

#define IN_FEAT 128
#define OUT_FEAT 64
#define LRELU_ALPHA 0.2f

// Kernel 1: h = x @ W  (one wave per row, lane = output column),
// fused s1[n] = h[n]·a1, s2[n] = h[n]·a2 via wave shuffle reduction.
__global__ __launch_bounds__(256) void gemm_score_kernel(
    const float* __restrict__ x, const float* __restrict__ W,
    const float* __restrict__ a, float* __restrict__ h,
    float* __restrict__ s1, float* __restrict__ s2, int N) {
  __shared__ float Wlds[IN_FEAT * OUT_FEAT];  // 32 KB
  for (int i = threadIdx.x; i < IN_FEAT * OUT_FEAT; i += 256) Wlds[i] = W[i];
  __syncthreads();

  int tid = blockIdx.x * 256 + threadIdx.x;
  int n = tid >> 6;
  int c = tid & 63;
  if (n >= N) return;

  const float4* x4 = (const float4*)(x + (size_t)n * IN_FEAT);
  float acc = 0.f;
#pragma unroll
  for (int j = 0; j < IN_FEAT / 4; ++j) {
    float4 xv = x4[j];  // wave-uniform broadcast load
    acc += xv.x * Wlds[(4 * j + 0) * OUT_FEAT + c];
    acc += xv.y * Wlds[(4 * j + 1) * OUT_FEAT + c];
    acc += xv.z * Wlds[(4 * j + 2) * OUT_FEAT + c];
    acc += xv.w * Wlds[(4 * j + 3) * OUT_FEAT + c];
  }
  h[(size_t)n * OUT_FEAT + c] = acc;

  float v1 = acc * a[c];
  float v2 = acc * a[OUT_FEAT + c];
#pragma unroll
  for (int off = 32; off > 0; off >>= 1) {
    v1 += __shfl_down(v1, off);
    v2 += __shfl_down(v2, off);
  }
  if (c == 0) {
    s1[n] = v1;
    s2[n] = v2;
  }
}

// Kernel 2: one wave per edge. Compute ee = exp(-leaky_relu(s1[src]+s2[dst])),
// scatter ee into rowsum[src] (lane 0) and ee*h[dst][c] into out[src][c].
__global__ __launch_bounds__(256) void edge_scatter_kernel(
    const int* __restrict__ src, const int* __restrict__ dst,
    const float* __restrict__ s1, const float* __restrict__ s2,
    const float* __restrict__ h, float* __restrict__ rowsum,
    float* __restrict__ out, int E) {
  int tid = blockIdx.x * 256 + threadIdx.x;
  int e = tid >> 6;
  int c = tid & 63;
  if (e >= E) return;

  int s = src[e];  // wave-uniform
  int d = dst[e];  // wave-uniform
  float sc = s1[s] + s2[d];
  float lr = sc > 0.f ? sc : LRELU_ALPHA * sc;
  float ee = expf(-lr);

  if (c == 0) atomicAdd(&rowsum[s], ee);
  float hv = h[(size_t)d * OUT_FEAT + c];  // coalesced 256B per wave
  atomicAdd(&out[(size_t)s * OUT_FEAT + c], ee * hv);
}

// Kernel 3: out = elu(out / rowsum) in place.
__global__ __launch_bounds__(256) void finalize_kernel(
    float* __restrict__ out, const float* __restrict__ rowsum, int N) {
  int tid = blockIdx.x * 256 + threadIdx.x;
  if (tid >= N * OUT_FEAT) return;
  float rs = rowsum[tid >> 6];
  float v = out[tid] / rs;
  out[tid] = v > 0.f ? v : expf(v) - 1.f;
}

extern "C" void kernel_launch(void* const* d_in, const int* in_sizes, int n_in,
                              void* d_out, int out_size, void* d_ws, size_t ws_size,
                              hipStream_t stream) {
  const float* x = (const float*)d_in[0];    // (N, 128) fp32
  const float* W = (const float*)d_in[1];    // (128, 64) fp32
  const float* a = (const float*)d_in[2];    // (1, 128) fp32
  const int* edge = (const int*)d_in[3];     // (2, E) int32

  const int N = in_sizes[0] / IN_FEAT;
  const int E = in_sizes[3] / 2;
  const int* src = edge;
  const int* dst = edge + E;

  float* out = (float*)d_out;                // (N, 64) fp32, used as h' accumulator

  // Workspace layout
  float* h  = (float*)d_ws;                  // N*64 floats = 25.6 MB
  float* s1 = h + (size_t)N * OUT_FEAT;      // N floats
  float* s2 = s1 + N;                        // N floats
  float* rowsum = s2 + N;                    // N floats

  // Zero accumulators (ws/out are poisoned 0xAA before every timed call)
  hipMemsetAsync(rowsum, 0, (size_t)N * sizeof(float), stream);
  hipMemsetAsync(out, 0, (size_t)out_size * sizeof(float), stream);

  int grid1 = (N * OUT_FEAT + 255) / 256;
  gemm_score_kernel<<<grid1, 256, 0, stream>>>(x, W, a, h, s1, s2, N);

  long long edge_threads = (long long)E * 64;
  int grid2 = (int)((edge_threads + 255) / 256);
  edge_scatter_kernel<<<grid2, 256, 0, stream>>>(src, dst, s1, s2, h, rowsum, out, E);

  finalize_kernel<<<grid1, 256, 0, stream>>>(out, rowsum, N);
}

// Round 2
// 531.687 us; speedup vs baseline: 1.2748x; 1.2748x over previous
//
#include <hip/hip_runtime.h>

#define IN_FEAT 128
#define OUT_FEAT 64
#define LRELU_ALPHA 0.2f

// ---------------------------------------------------------------------------
// Kernel 1: h = x @ W (one wave per row, lane = output column),
// fused s1[n] = h[n]·a1, s2[n] = h[n]·a2 via wave shuffle reduction.
// ---------------------------------------------------------------------------
__global__ __launch_bounds__(256) void gemm_score_kernel(
    const float* __restrict__ x, const float* __restrict__ W,
    const float* __restrict__ a, float* __restrict__ h,
    float* __restrict__ s1, float* __restrict__ s2, int N) {
  __shared__ float Wlds[IN_FEAT * OUT_FEAT];  // 32 KB
  for (int i = threadIdx.x; i < IN_FEAT * OUT_FEAT; i += 256) Wlds[i] = W[i];
  __syncthreads();

  int tid = blockIdx.x * 256 + threadIdx.x;
  int n = tid >> 6;
  int c = tid & 63;
  if (n >= N) return;

  const float4* x4 = (const float4*)(x + (size_t)n * IN_FEAT);
  float acc = 0.f;
#pragma unroll
  for (int j = 0; j < IN_FEAT / 4; ++j) {
    float4 xv = x4[j];  // wave-uniform broadcast load
    acc += xv.x * Wlds[(4 * j + 0) * OUT_FEAT + c];
    acc += xv.y * Wlds[(4 * j + 1) * OUT_FEAT + c];
    acc += xv.z * Wlds[(4 * j + 2) * OUT_FEAT + c];
    acc += xv.w * Wlds[(4 * j + 3) * OUT_FEAT + c];
  }
  h[(size_t)n * OUT_FEAT + c] = acc;

  float v1 = acc * a[c];
  float v2 = acc * a[OUT_FEAT + c];
#pragma unroll
  for (int off = 32; off > 0; off >>= 1) {
    v1 += __shfl_down(v1, off);
    v2 += __shfl_down(v2, off);
  }
  if (c == 0) {
    s1[n] = v1;
    s2[n] = v2;
  }
}

// ---------------------------------------------------------------------------
// Counting-sort by src: histogram -> exclusive scan -> scatter edge records.
// ---------------------------------------------------------------------------
__global__ __launch_bounds__(256) void hist_kernel(
    const int* __restrict__ src, int* __restrict__ counts, int E) {
  int e = blockIdx.x * 256 + threadIdx.x;
  if (e < E) atomicAdd(&counts[src[e]], 1);
}

// Per-block partial sums (1024 counts per block).
__global__ __launch_bounds__(256) void scan_reduce_kernel(
    const int* __restrict__ counts, int* __restrict__ bsums, int N) {
  __shared__ int wsum[4];
  int base = blockIdx.x * 1024 + threadIdx.x * 4;
  int s = 0;
#pragma unroll
  for (int j = 0; j < 4; ++j)
    if (base + j < N) s += counts[base + j];
#pragma unroll
  for (int off = 32; off > 0; off >>= 1) s += __shfl_down(s, off);
  int lane = threadIdx.x & 63, w = threadIdx.x >> 6;
  if (lane == 0) wsum[w] = s;
  __syncthreads();
  if (threadIdx.x == 0)
    bsums[blockIdx.x] = wsum[0] + wsum[1] + wsum[2] + wsum[3];
}

// Exclusive scan of the (~98) block sums in one small block.
__global__ __launch_bounds__(256) void scan_bsums_kernel(int* __restrict__ bsums, int NB) {
  __shared__ int lds[256];
  int t = threadIdx.x;
  lds[t] = (t < NB) ? bsums[t] : 0;
  __syncthreads();
  if (t == 0) {
    int run = 0;
    for (int i = 0; i < NB; ++i) { int v = lds[i]; lds[i] = run; run += v; }
  }
  __syncthreads();
  if (t < NB) bsums[t] = lds[t];
}

// Recompute per-block scan, add block offset, write row_start + cursor copy.
__global__ __launch_bounds__(256) void scan_write_kernel(
    const int* __restrict__ counts, const int* __restrict__ bsums,
    int* __restrict__ row_start, int* __restrict__ cursor, int N) {
  __shared__ int wtot[4];
  int base = blockIdx.x * 1024 + threadIdx.x * 4;
  int v[4];
  int ts = 0;
#pragma unroll
  for (int j = 0; j < 4; ++j) {
    v[j] = (base + j < N) ? counts[base + j] : 0;
    ts += v[j];
  }
  int lane = threadIdx.x & 63, w = threadIdx.x >> 6;
  // inclusive wave scan of ts
  int x = ts;
#pragma unroll
  for (int off = 1; off < 64; off <<= 1) {
    int y = __shfl_up(x, off);
    if (lane >= off) x += y;
  }
  if (lane == 63) wtot[w] = x;
  __syncthreads();
  int woff = 0;
  for (int i = 0; i < w; ++i) woff += wtot[i];
  int run = bsums[blockIdx.x] + woff + (x - ts);  // exclusive start for elem 0
#pragma unroll
  for (int j = 0; j < 4; ++j) {
    if (base + j < N) {
      row_start[base + j] = run;
      cursor[base + j] = run;
    }
    run += v[j];
  }
}

// Scatter: one thread per edge. Compute ee, place record into src's slot range.
__global__ __launch_bounds__(256) void scatter_kernel(
    const int* __restrict__ src, const int* __restrict__ dst,
    const float* __restrict__ s1, const float* __restrict__ s2,
    int* __restrict__ cursor, int2* __restrict__ rec, int E) {
  int e = blockIdx.x * 256 + threadIdx.x;
  if (e >= E) return;
  int s = src[e], d = dst[e];
  float sc = s1[s] + s2[d];
  float lr = sc > 0.f ? sc : LRELU_ALPHA * sc;
  float ee = expf(-lr);
  int pos = atomicAdd(&cursor[s], 1);
  rec[pos] = make_int2(d, __float_as_int(ee));
}

// ---------------------------------------------------------------------------
// Kernel 3: atomic-free aggregate. One wave per node: walk its edge records,
// acc[c] += ee * h[dst][c]; rowsum += ee (uniform across lanes, no reduction
// needed). Fused finalize: out = elu(acc / rowsum).
// ---------------------------------------------------------------------------
__global__ __launch_bounds__(256) void node_aggregate_kernel(
    const int2* __restrict__ rec, const int* __restrict__ row_start,
    const int* __restrict__ counts, const float* __restrict__ h,
    float* __restrict__ out, int N) {
  int tid = blockIdx.x * 256 + threadIdx.x;
  int n = tid >> 6;
  int c = tid & 63;
  if (n >= N) return;

  int start = row_start[n];
  int cnt = counts[n];
  float acc = 0.f, rs = 0.f;
  for (int i = 0; i < cnt; ++i) {
    int2 r = rec[start + i];       // 8B broadcast load (wave-uniform)
    float ee = __int_as_float(r.y);
    rs += ee;
    acc += ee * h[(size_t)r.x * OUT_FEAT + c];  // coalesced 256B gather
  }
  float v = acc / rs;
  out[(size_t)n * OUT_FEAT + c] = v > 0.f ? v : expf(v) - 1.f;
}

extern "C" void kernel_launch(void* const* d_in, const int* in_sizes, int n_in,
                              void* d_out, int out_size, void* d_ws, size_t ws_size,
                              hipStream_t stream) {
  const float* x = (const float*)d_in[0];    // (N, 128) fp32
  const float* W = (const float*)d_in[1];    // (128, 64) fp32
  const float* a = (const float*)d_in[2];    // (1, 128) fp32
  const int* edge = (const int*)d_in[3];     // (2, E) int32

  const int N = in_sizes[0] / IN_FEAT;
  const int E = in_sizes[3] / 2;
  const int* src = edge;
  const int* dst = edge + E;

  float* out = (float*)d_out;                // (N, 64) fp32

  // Workspace layout
  char* p = (char*)d_ws;
  float* h = (float*)p;            p += (size_t)N * OUT_FEAT * sizeof(float);  // 25.6 MB
  float* s1 = (float*)p;           p += (size_t)N * sizeof(float);
  float* s2 = (float*)p;           p += (size_t)N * sizeof(float);
  int* counts = (int*)p;           p += (size_t)N * sizeof(int);
  int* row_start = (int*)p;        p += (size_t)N * sizeof(int);
  int* cursor = (int*)p;           p += (size_t)N * sizeof(int);
  int* bsums = (int*)p;            p += 1024 * sizeof(int);
  int2* rec = (int2*)p;            p += (size_t)E * sizeof(int2);               // 12.8 MB

  const int NB = (N + 1023) / 1024;  // blocks for the scan kernels

  hipMemsetAsync(counts, 0, (size_t)N * sizeof(int), stream);

  int grid_rows = (N * OUT_FEAT + 255) / 256;
  gemm_score_kernel<<<grid_rows, 256, 0, stream>>>(x, W, a, h, s1, s2, N);

  int grid_e = (E + 255) / 256;
  hist_kernel<<<grid_e, 256, 0, stream>>>(src, counts, E);
  scan_reduce_kernel<<<NB, 256, 0, stream>>>(counts, bsums, N);
  scan_bsums_kernel<<<1, 256, 0, stream>>>(bsums, NB);
  scan_write_kernel<<<NB, 256, 0, stream>>>(counts, bsums, row_start, cursor, N);
  scatter_kernel<<<grid_e, 256, 0, stream>>>(src, dst, s1, s2, cursor, rec, E);

  node_aggregate_kernel<<<grid_rows, 256, 0, stream>>>(rec, row_start, counts, h, out, N);
}

// Round 3
// 365.715 us; speedup vs baseline: 1.8533x; 1.4538x over previous
//
#include <hip/hip_runtime.h>

#define IN_FEAT 128
#define OUT_FEAT 64
#define LRELU_ALPHA 0.2f

typedef __attribute__((ext_vector_type(8))) short bf16x8;
typedef __attribute__((ext_vector_type(4))) float floatx4;

// fp32 -> bf16 bits, round-to-nearest-even (inputs are finite; no NaN guard)
__device__ __forceinline__ short f2bf(float f) {
  union { float f; unsigned u; } v; v.f = f;
  unsigned r = v.u + 0x7fff + ((v.u >> 16) & 1);
  return (short)(r >> 16);
}
__device__ __forceinline__ float bf2f(unsigned short s) {
  union { unsigned u; float f; } v; v.u = ((unsigned)s) << 16;
  return v.f;
}

// ---------------------------------------------------------------------------
// Kernel 1: h = bf16(x) @ bf16(W) via MFMA 16x16x32. Block = 4 waves = 64 rows.
// Fused: s1 = h@a1, s2 = h@a2 (quad shuffle reduction). h stored as bf16 bits.
// ---------------------------------------------------------------------------
__global__ __launch_bounds__(256) void gemm_mfma_kernel(
    const float* __restrict__ x, const float* __restrict__ W,
    const float* __restrict__ a, unsigned short* __restrict__ h,
    float* __restrict__ s1, float* __restrict__ s2, int N) {
  // W^T in LDS as bf16, row stride 136 shorts (272B) to break bank conflicts.
  __shared__ __align__(16) short Wt[64 * 136];
  __shared__ float a_sh[2 * OUT_FEAT];

  if (threadIdx.x < 2 * OUT_FEAT) a_sh[threadIdx.x] = a[threadIdx.x];
  for (int i = threadIdx.x; i < IN_FEAT * OUT_FEAT; i += 256) {
    int k = i >> 6, n = i & 63;
    Wt[n * 136 + k] = f2bf(W[i]);
  }
  __syncthreads();

  int wave = threadIdx.x >> 6;
  int lane = threadIdx.x & 63;
  int l = lane & 15;     // 0..15
  int quad = lane >> 4;  // 0..3

  int row_base = blockIdx.x * 64 + wave * 16;  // wave covers rows row_base..+15
  int m = row_base + l;
  int m_c = m < N ? m : N - 1;  // clamp OOB loads (stores are guarded)

  // Preload all B fragments: B[k=kt*32+quad*8+j][n=nt*16+l] = Wt[n][k]
  bf16x8 bfrag[4][4];
#pragma unroll
  for (int kt = 0; kt < 4; ++kt)
#pragma unroll
    for (int nt = 0; nt < 4; ++nt)
      bfrag[kt][nt] = *(const bf16x8*)&Wt[(nt * 16 + l) * 136 + kt * 32 + quad * 8];

  floatx4 acc[4] = {floatx4{0,0,0,0}, floatx4{0,0,0,0}, floatx4{0,0,0,0}, floatx4{0,0,0,0}};
  const float* xrow = x + (size_t)m_c * IN_FEAT;
#pragma unroll
  for (int kt = 0; kt < 4; ++kt) {
    // A[m=l][k=kt*32+quad*8+j]: 8 consecutive fp32 -> bf16
    float4 xa = *(const float4*)(xrow + kt * 32 + quad * 8);
    float4 xb = *(const float4*)(xrow + kt * 32 + quad * 8 + 4);
    bf16x8 af;
    af[0] = f2bf(xa.x); af[1] = f2bf(xa.y); af[2] = f2bf(xa.z); af[3] = f2bf(xa.w);
    af[4] = f2bf(xb.x); af[5] = f2bf(xb.y); af[6] = f2bf(xb.z); af[7] = f2bf(xb.w);
#pragma unroll
    for (int nt = 0; nt < 4; ++nt)
      acc[nt] = __builtin_amdgcn_mfma_f32_16x16x32_bf16(af, bfrag[kt][nt], acc[nt], 0, 0, 0);
  }

  // C/D layout: col = nt*16 + (lane&15), row = row_base + quad*4 + reg.
  int out_row = row_base + quad * 4;
#pragma unroll
  for (int reg = 0; reg < 4; ++reg) {
    int r = out_row + reg;
    if (r < N) {
#pragma unroll
      for (int nt = 0; nt < 4; ++nt)
        h[(size_t)r * OUT_FEAT + nt * 16 + l] = (unsigned short)f2bf(acc[nt][reg]);
    }
  }

  // s1/s2: row dot a1/a2. Lane partial over its 4 cols, reduce over 16 lanes.
  float p1[4] = {0, 0, 0, 0}, p2[4] = {0, 0, 0, 0};
#pragma unroll
  for (int nt = 0; nt < 4; ++nt) {
    float a1v = a_sh[nt * 16 + l];
    float a2v = a_sh[OUT_FEAT + nt * 16 + l];
#pragma unroll
    for (int reg = 0; reg < 4; ++reg) {
      p1[reg] += acc[nt][reg] * a1v;
      p2[reg] += acc[nt][reg] * a2v;
    }
  }
#pragma unroll
  for (int off = 1; off < 16; off <<= 1) {
#pragma unroll
    for (int reg = 0; reg < 4; ++reg) {
      p1[reg] += __shfl_xor(p1[reg], off);
      p2[reg] += __shfl_xor(p2[reg], off);
    }
  }
  if (l < 4) {
    int r = out_row + l;
    if (r < N) {
      float v1 = l == 0 ? p1[0] : (l == 1 ? p1[1] : (l == 2 ? p1[2] : p1[3]));
      float v2 = l == 0 ? p2[0] : (l == 1 ? p2[1] : (l == 2 ? p2[2] : p2[3]));
      s1[r] = v1;
      s2[r] = v2;
    }
  }
}

// ---------------------------------------------------------------------------
// Counting-sort by src: histogram -> exclusive scan -> scatter dst indices.
// ---------------------------------------------------------------------------
__global__ __launch_bounds__(256) void hist_kernel(
    const int* __restrict__ src, int* __restrict__ counts, int E) {
  int e = blockIdx.x * 256 + threadIdx.x;
  if (e < E) atomicAdd(&counts[src[e]], 1);
}

__global__ __launch_bounds__(256) void scan_reduce_kernel(
    const int* __restrict__ counts, int* __restrict__ bsums, int N) {
  __shared__ int wsum[4];
  int base = blockIdx.x * 1024 + threadIdx.x * 4;
  int s = 0;
#pragma unroll
  for (int j = 0; j < 4; ++j)
    if (base + j < N) s += counts[base + j];
#pragma unroll
  for (int off = 32; off > 0; off >>= 1) s += __shfl_down(s, off);
  int lane = threadIdx.x & 63, w = threadIdx.x >> 6;
  if (lane == 0) wsum[w] = s;
  __syncthreads();
  if (threadIdx.x == 0)
    bsums[blockIdx.x] = wsum[0] + wsum[1] + wsum[2] + wsum[3];
}

__global__ __launch_bounds__(256) void scan_bsums_kernel(int* __restrict__ bsums, int NB) {
  __shared__ int lds[256];
  int t = threadIdx.x;
  lds[t] = (t < NB) ? bsums[t] : 0;
  __syncthreads();
  if (t == 0) {
    int run = 0;
    for (int i = 0; i < NB; ++i) { int v = lds[i]; lds[i] = run; run += v; }
  }
  __syncthreads();
  if (t < NB) bsums[t] = lds[t];
}

__global__ __launch_bounds__(256) void scan_write_kernel(
    const int* __restrict__ counts, const int* __restrict__ bsums,
    int* __restrict__ row_start, int* __restrict__ cursor, int N) {
  __shared__ int wtot[4];
  int base = blockIdx.x * 1024 + threadIdx.x * 4;
  int v[4];
  int ts = 0;
#pragma unroll
  for (int j = 0; j < 4; ++j) {
    v[j] = (base + j < N) ? counts[base + j] : 0;
    ts += v[j];
  }
  int lane = threadIdx.x & 63, w = threadIdx.x >> 6;
  int xs = ts;
#pragma unroll
  for (int off = 1; off < 64; off <<= 1) {
    int y = __shfl_up(xs, off);
    if (lane >= off) xs += y;
  }
  if (lane == 63) wtot[w] = xs;
  __syncthreads();
  int woff = 0;
  for (int i = 0; i < w; ++i) woff += wtot[i];
  int run = bsums[blockIdx.x] + woff + (xs - ts);
#pragma unroll
  for (int j = 0; j < 4; ++j) {
    if (base + j < N) {
      row_start[base + j] = run;
      cursor[base + j] = run;
    }
    run += v[j];
  }
}

// Scatter: one thread per edge; rec[pos] = dst only (ee recomputed later).
__global__ __launch_bounds__(256) void scatter_kernel(
    const int* __restrict__ src, const int* __restrict__ dst,
    int* __restrict__ cursor, int* __restrict__ rec, int E) {
  int e = blockIdx.x * 256 + threadIdx.x;
  if (e >= E) return;
  int s = src[e], d = dst[e];
  int pos = atomicAdd(&cursor[s], 1);
  rec[pos] = d;
}

// ---------------------------------------------------------------------------
// Kernel 3: atomic-free aggregate, one wave per node, 4 edges in flight.
// ee = exp(-lrelu(s1[n] + s2[d])) recomputed here (s1[n] wave-uniform,
// s2[d] broadcast load). Fused finalize: out = elu(acc / rowsum).
// ---------------------------------------------------------------------------
__global__ __launch_bounds__(256) void node_aggregate_kernel(
    const int* __restrict__ rec, const int* __restrict__ row_start,
    const int* __restrict__ counts, const unsigned short* __restrict__ h,
    const float* __restrict__ s1, const float* __restrict__ s2,
    float* __restrict__ out, int N) {
  int tid = blockIdx.x * 256 + threadIdx.x;
  int n = tid >> 6;
  int c = tid & 63;
  if (n >= N) return;

  int start = row_start[n];
  int cnt = counts[n];
  float s1n = s1[n];
  float acc = 0.f, rs = 0.f;

  int i = 0;
  for (; i + 4 <= cnt; i += 4) {
    int d0 = rec[start + i + 0];
    int d1 = rec[start + i + 1];
    int d2 = rec[start + i + 2];
    int d3 = rec[start + i + 3];
    float t0 = s2[d0], t1 = s2[d1], t2 = s2[d2], t3 = s2[d3];
    unsigned short h0 = h[(size_t)d0 * OUT_FEAT + c];
    unsigned short h1 = h[(size_t)d1 * OUT_FEAT + c];
    unsigned short h2 = h[(size_t)d2 * OUT_FEAT + c];
    unsigned short h3 = h[(size_t)d3 * OUT_FEAT + c];
    float sc0 = s1n + t0, sc1 = s1n + t1, sc2 = s1n + t2, sc3 = s1n + t3;
    float e0 = __expf(-(sc0 > 0.f ? sc0 : LRELU_ALPHA * sc0));
    float e1 = __expf(-(sc1 > 0.f ? sc1 : LRELU_ALPHA * sc1));
    float e2 = __expf(-(sc2 > 0.f ? sc2 : LRELU_ALPHA * sc2));
    float e3 = __expf(-(sc3 > 0.f ? sc3 : LRELU_ALPHA * sc3));
    rs += (e0 + e1) + (e2 + e3);
    acc += e0 * bf2f(h0) + e1 * bf2f(h1) + e2 * bf2f(h2) + e3 * bf2f(h3);
  }
  for (; i < cnt; ++i) {
    int d = rec[start + i];
    float sc = s1n + s2[d];
    float ee = __expf(-(sc > 0.f ? sc : LRELU_ALPHA * sc));
    rs += ee;
    acc += ee * bf2f(h[(size_t)d * OUT_FEAT + c]);
  }

  float v = acc / rs;
  out[(size_t)n * OUT_FEAT + c] = v > 0.f ? v : __expf(v) - 1.f;
}

extern "C" void kernel_launch(void* const* d_in, const int* in_sizes, int n_in,
                              void* d_out, int out_size, void* d_ws, size_t ws_size,
                              hipStream_t stream) {
  const float* x = (const float*)d_in[0];  // (N, 128) fp32
  const float* W = (const float*)d_in[1];  // (128, 64) fp32
  const float* a = (const float*)d_in[2];  // (1, 128) fp32
  const int* edge = (const int*)d_in[3];   // (2, E) int32

  const int N = in_sizes[0] / IN_FEAT;
  const int E = in_sizes[3] / 2;
  const int* src = edge;
  const int* dst = edge + E;

  float* out = (float*)d_out;  // (N, 64) fp32

  // Workspace layout
  char* p = (char*)d_ws;
  unsigned short* h = (unsigned short*)p; p += (size_t)N * OUT_FEAT * sizeof(unsigned short); // 12.8 MB
  float* s1 = (float*)p;      p += (size_t)N * sizeof(float);
  float* s2 = (float*)p;      p += (size_t)N * sizeof(float);
  int* counts = (int*)p;      p += (size_t)N * sizeof(int);
  int* row_start = (int*)p;   p += (size_t)N * sizeof(int);
  int* cursor = (int*)p;      p += (size_t)N * sizeof(int);
  int* bsums = (int*)p;       p += 1024 * sizeof(int);
  int* rec = (int*)p;         p += (size_t)E * sizeof(int);  // 6.4 MB

  const int NB = (N + 1023) / 1024;

  hipMemsetAsync(counts, 0, (size_t)N * sizeof(int), stream);

  int grid_gemm = (N + 63) / 64;
  gemm_mfma_kernel<<<grid_gemm, 256, 0, stream>>>(x, W, a, h, s1, s2, N);

  int grid_e = (E + 255) / 256;
  hist_kernel<<<grid_e, 256, 0, stream>>>(src, counts, E);
  scan_reduce_kernel<<<NB, 256, 0, stream>>>(counts, bsums, N);
  scan_bsums_kernel<<<1, 256, 0, stream>>>(bsums, NB);
  scan_write_kernel<<<NB, 256, 0, stream>>>(counts, bsums, row_start, cursor, N);
  scatter_kernel<<<grid_e, 256, 0, stream>>>(src, dst, cursor, rec, E);

  int grid_rows = (N * OUT_FEAT + 255) / 256;
  node_aggregate_kernel<<<grid_rows, 256, 0, stream>>>(rec, row_start, counts, h, s1, s2, out, N);
}

// Round 4
// 311.739 us; speedup vs baseline: 2.1742x; 1.1731x over previous
//
#include <hip/hip_runtime.h>

#define IN_FEAT 128
#define OUT_FEAT 64
#define LRELU_ALPHA 0.2f
#define BUK_SHIFT 10     // coarse bucket = src >> 10 (1024 nodes/bucket)
#define MAX_NBUK 128     // N <= 131072
#define BIN_PER_THREAD 8 // 2048 edges per bin block

typedef __attribute__((ext_vector_type(8))) short bf16x8;
typedef __attribute__((ext_vector_type(4))) float floatx4;

// fp32 -> bf16 bits, round-to-nearest-even (inputs are finite; no NaN guard)
__device__ __forceinline__ short f2bf(float f) {
  union { float f; unsigned u; } v; v.f = f;
  unsigned r = v.u + 0x7fff + ((v.u >> 16) & 1);
  return (short)(r >> 16);
}
__device__ __forceinline__ float bf2f(unsigned short s) {
  union { unsigned u; float f; } v; v.u = ((unsigned)s) << 16;
  return v.f;
}

// ---------------------------------------------------------------------------
// Kernel 1: h = bf16(x) @ bf16(W) via MFMA 16x16x32. Block = 4 waves = 64 rows.
// Fused: s1 = h@a1, s2 = h@a2 (quad shuffle reduction). h stored as bf16 bits.
// ---------------------------------------------------------------------------
__global__ __launch_bounds__(256) void gemm_mfma_kernel(
    const float* __restrict__ x, const float* __restrict__ W,
    const float* __restrict__ a, unsigned short* __restrict__ h,
    float* __restrict__ s1, float* __restrict__ s2, int N) {
  __shared__ __align__(16) short Wt[64 * 136];  // W^T bf16, stride 136
  __shared__ float a_sh[2 * OUT_FEAT];

  if (threadIdx.x < 2 * OUT_FEAT) a_sh[threadIdx.x] = a[threadIdx.x];
  for (int i = threadIdx.x; i < IN_FEAT * OUT_FEAT; i += 256) {
    int k = i >> 6, n = i & 63;
    Wt[n * 136 + k] = f2bf(W[i]);
  }
  __syncthreads();

  int wave = threadIdx.x >> 6;
  int lane = threadIdx.x & 63;
  int l = lane & 15;
  int quad = lane >> 4;

  int row_base = blockIdx.x * 64 + wave * 16;
  int m = row_base + l;
  int m_c = m < N ? m : N - 1;

  bf16x8 bfrag[4][4];
#pragma unroll
  for (int kt = 0; kt < 4; ++kt)
#pragma unroll
    for (int nt = 0; nt < 4; ++nt)
      bfrag[kt][nt] = *(const bf16x8*)&Wt[(nt * 16 + l) * 136 + kt * 32 + quad * 8];

  floatx4 acc[4] = {floatx4{0,0,0,0}, floatx4{0,0,0,0}, floatx4{0,0,0,0}, floatx4{0,0,0,0}};
  const float* xrow = x + (size_t)m_c * IN_FEAT;
#pragma unroll
  for (int kt = 0; kt < 4; ++kt) {
    float4 xa = *(const float4*)(xrow + kt * 32 + quad * 8);
    float4 xb = *(const float4*)(xrow + kt * 32 + quad * 8 + 4);
    bf16x8 af;
    af[0] = f2bf(xa.x); af[1] = f2bf(xa.y); af[2] = f2bf(xa.z); af[3] = f2bf(xa.w);
    af[4] = f2bf(xb.x); af[5] = f2bf(xb.y); af[6] = f2bf(xb.z); af[7] = f2bf(xb.w);
#pragma unroll
    for (int nt = 0; nt < 4; ++nt)
      acc[nt] = __builtin_amdgcn_mfma_f32_16x16x32_bf16(af, bfrag[kt][nt], acc[nt], 0, 0, 0);
  }

  int out_row = row_base + quad * 4;
#pragma unroll
  for (int reg = 0; reg < 4; ++reg) {
    int r = out_row + reg;
    if (r < N) {
#pragma unroll
      for (int nt = 0; nt < 4; ++nt)
        h[(size_t)r * OUT_FEAT + nt * 16 + l] = (unsigned short)f2bf(acc[nt][reg]);
    }
  }

  float p1[4] = {0, 0, 0, 0}, p2[4] = {0, 0, 0, 0};
#pragma unroll
  for (int nt = 0; nt < 4; ++nt) {
    float a1v = a_sh[nt * 16 + l];
    float a2v = a_sh[OUT_FEAT + nt * 16 + l];
#pragma unroll
    for (int reg = 0; reg < 4; ++reg) {
      p1[reg] += acc[nt][reg] * a1v;
      p2[reg] += acc[nt][reg] * a2v;
    }
  }
#pragma unroll
  for (int off = 1; off < 16; off <<= 1) {
#pragma unroll
    for (int reg = 0; reg < 4; ++reg) {
      p1[reg] += __shfl_xor(p1[reg], off);
      p2[reg] += __shfl_xor(p2[reg], off);
    }
  }
  if (l < 4) {
    int r = out_row + l;
    if (r < N) {
      float v1 = l == 0 ? p1[0] : (l == 1 ? p1[1] : (l == 2 ? p1[2] : p1[3]));
      float v2 = l == 0 ? p2[0] : (l == 1 ? p2[1] : (l == 2 ? p2[2] : p2[3]));
      s1[r] = v1;
      s2[r] = v2;
    }
  }
}

// ---------------------------------------------------------------------------
// Per-node histogram of src.
// ---------------------------------------------------------------------------
__global__ __launch_bounds__(256) void hist_kernel(
    const int* __restrict__ src, int* __restrict__ counts, int E) {
  int e = blockIdx.x * 256 + threadIdx.x;
  if (e < E) atomicAdd(&counts[src[e]], 1);
}

// Per-1024-node partial sums -> bsums. These double as the coarse bucket hist.
__global__ __launch_bounds__(256) void scan_reduce_kernel(
    const int* __restrict__ counts, int* __restrict__ bsums, int N) {
  __shared__ int wsum[4];
  int base = blockIdx.x * 1024 + threadIdx.x * 4;
  int s = 0;
#pragma unroll
  for (int j = 0; j < 4; ++j)
    if (base + j < N) s += counts[base + j];
#pragma unroll
  for (int off = 32; off > 0; off >>= 1) s += __shfl_down(s, off);
  int lane = threadIdx.x & 63, w = threadIdx.x >> 6;
  if (lane == 0) wsum[w] = s;
  __syncthreads();
  if (threadIdx.x == 0)
    bsums[blockIdx.x] = wsum[0] + wsum[1] + wsum[2] + wsum[3];
}

// Exclusive scan of bsums in place; also emit mutable copy as bucket cursors.
__global__ __launch_bounds__(256) void scan_bsums_kernel(
    int* __restrict__ bsums, int* __restrict__ buk_cursor, int NB) {
  __shared__ int lds[MAX_NBUK];
  int t = threadIdx.x;
  if (t < NB) lds[t] = bsums[t];
  __syncthreads();
  if (t == 0) {
    int run = 0;
    for (int i = 0; i < NB; ++i) { int v = lds[i]; lds[i] = run; run += v; }
  }
  __syncthreads();
  if (t < NB) {
    bsums[t] = lds[t];
    buk_cursor[t] = lds[t];
  }
}

// Per-node exclusive scan -> row_start + cursor copy.
__global__ __launch_bounds__(256) void scan_write_kernel(
    const int* __restrict__ counts, const int* __restrict__ bsums,
    int* __restrict__ row_start, int* __restrict__ cursor, int N) {
  __shared__ int wtot[4];
  int base = blockIdx.x * 1024 + threadIdx.x * 4;
  int v[4];
  int ts = 0;
#pragma unroll
  for (int j = 0; j < 4; ++j) {
    v[j] = (base + j < N) ? counts[base + j] : 0;
    ts += v[j];
  }
  int lane = threadIdx.x & 63, w = threadIdx.x >> 6;
  int xs = ts;
#pragma unroll
  for (int off = 1; off < 64; off <<= 1) {
    int y = __shfl_up(xs, off);
    if (lane >= off) xs += y;
  }
  if (lane == 63) wtot[w] = xs;
  __syncthreads();
  int woff = 0;
  for (int i = 0; i < w; ++i) woff += wtot[i];
  int run = bsums[blockIdx.x] + woff + (xs - ts);
#pragma unroll
  for (int j = 0; j < 4; ++j) {
    if (base + j < N) {
      row_start[base + j] = run;
      cursor[base + j] = run;
    }
    run += v[j];
  }
}

// ---------------------------------------------------------------------------
// Phase 1: coarse bin by src>>10. Per-block LDS histogram + one global atomic
// per (block,bucket) reservation -> contiguous ~168B write runs per bucket.
// ---------------------------------------------------------------------------
__global__ __launch_bounds__(256) void bin_kernel(
    const int* __restrict__ src, const int* __restrict__ dst,
    int* __restrict__ buk_cursor, int2* __restrict__ bukdata, int E) {
  __shared__ int lhist[MAX_NBUK];
  __shared__ int lbase[MAX_NBUK];
  int t = threadIdx.x;
  for (int i = t; i < MAX_NBUK; i += 256) lhist[i] = 0;
  __syncthreads();

  int base_e = blockIdx.x * (256 * BIN_PER_THREAD);
  int s[BIN_PER_THREAD], d[BIN_PER_THREAD], b[BIN_PER_THREAD];
#pragma unroll
  for (int j = 0; j < BIN_PER_THREAD; ++j) {
    int e = base_e + j * 256 + t;
    bool valid = e < E;
    s[j] = valid ? src[e] : 0;
    d[j] = valid ? dst[e] : 0;
    b[j] = s[j] >> BUK_SHIFT;
    if (valid) atomicAdd(&lhist[b[j]], 1);
  }
  __syncthreads();
  for (int i = t; i < MAX_NBUK; i += 256) {
    int c = lhist[i];
    lbase[i] = c > 0 ? atomicAdd(&buk_cursor[i], c) : 0;
    lhist[i] = 0;  // reuse as in-block cursor
  }
  __syncthreads();
#pragma unroll
  for (int j = 0; j < BIN_PER_THREAD; ++j) {
    int e = base_e + j * 256 + t;
    if (e < E) {
      int pos = lbase[b[j]] + atomicAdd(&lhist[b[j]], 1);
      bukdata[pos] = make_int2(s[j], d[j]);
    }
  }
}

// ---------------------------------------------------------------------------
// Phase 2: fine scatter. Input is bucket-sorted, so cursor atomics hit a 4KB
// window and rec writes a ~65KB window per bucket -> L2-resident, lines merge.
// ---------------------------------------------------------------------------
__global__ __launch_bounds__(256) void fine_scatter_kernel(
    const int2* __restrict__ bukdata, int* __restrict__ cursor,
    int* __restrict__ rec, int E) {
  int e = blockIdx.x * 256 + threadIdx.x;
  if (e >= E) return;
  int2 p = bukdata[e];
  int pos = atomicAdd(&cursor[p.x], 1);
  rec[pos] = p.y;
}

// ---------------------------------------------------------------------------
// Kernel 3: atomic-free aggregate. One wave per node; bf16 h row = 128B =
// 32 lanes x ushort2, so the two wave-halves process alternating edges
// (8 gathers in flight with the x4 unroll). Cross-half shfl_xor(32) reduce.
// Fused finalize: out = elu(acc / rowsum).
// ---------------------------------------------------------------------------
__global__ __launch_bounds__(256) void node_aggregate_kernel(
    const int* __restrict__ rec, const int* __restrict__ row_start,
    const int* __restrict__ counts, const unsigned short* __restrict__ h,
    const float* __restrict__ s1, const float* __restrict__ s2,
    float* __restrict__ out, int N) {
  int tid = blockIdx.x * 256 + threadIdx.x;
  int n = tid >> 6;
  if (n >= N) return;
  int lane = threadIdx.x & 63;
  int half = lane >> 5;  // which edge of the pair
  int c2 = lane & 31;    // column-pair index

  int start = row_start[n];
  int cnt = counts[n];
  float s1n = s1[n];
  float ax = 0.f, ay = 0.f, rs = 0.f;

  int i = 0;
  for (; i + 8 <= cnt; i += 8) {
    int b0 = start + i + half;
    int d0 = rec[b0], d1 = rec[b0 + 2], d2 = rec[b0 + 4], d3 = rec[b0 + 6];
    float t0 = s2[d0], t1 = s2[d1], t2 = s2[d2], t3 = s2[d3];
    unsigned v0 = *(const unsigned*)&h[(size_t)d0 * OUT_FEAT + 2 * c2];
    unsigned v1 = *(const unsigned*)&h[(size_t)d1 * OUT_FEAT + 2 * c2];
    unsigned v2 = *(const unsigned*)&h[(size_t)d2 * OUT_FEAT + 2 * c2];
    unsigned v3 = *(const unsigned*)&h[(size_t)d3 * OUT_FEAT + 2 * c2];
    float sc0 = s1n + t0, sc1 = s1n + t1, sc2 = s1n + t2, sc3 = s1n + t3;
    float e0 = __expf(-(sc0 > 0.f ? sc0 : LRELU_ALPHA * sc0));
    float e1 = __expf(-(sc1 > 0.f ? sc1 : LRELU_ALPHA * sc1));
    float e2 = __expf(-(sc2 > 0.f ? sc2 : LRELU_ALPHA * sc2));
    float e3 = __expf(-(sc3 > 0.f ? sc3 : LRELU_ALPHA * sc3));
    rs += (e0 + e1) + (e2 + e3);
    ax += e0 * bf2f(v0 & 0xffff) + e1 * bf2f(v1 & 0xffff) +
          e2 * bf2f(v2 & 0xffff) + e3 * bf2f(v3 & 0xffff);
    ay += e0 * bf2f(v0 >> 16) + e1 * bf2f(v1 >> 16) +
          e2 * bf2f(v2 >> 16) + e3 * bf2f(v3 >> 16);
  }
  for (; i + 2 <= cnt; i += 2) {
    int d = rec[start + i + half];
    float sc = s1n + s2[d];
    unsigned v = *(const unsigned*)&h[(size_t)d * OUT_FEAT + 2 * c2];
    float ee = __expf(-(sc > 0.f ? sc : LRELU_ALPHA * sc));
    rs += ee;
    ax += ee * bf2f(v & 0xffff);
    ay += ee * bf2f(v >> 16);
  }
  if (i < cnt && half == 0) {
    int d = rec[start + i];
    float sc = s1n + s2[d];
    unsigned v = *(const unsigned*)&h[(size_t)d * OUT_FEAT + 2 * c2];
    float ee = __expf(-(sc > 0.f ? sc : LRELU_ALPHA * sc));
    rs += ee;
    ax += ee * bf2f(v & 0xffff);
    ay += ee * bf2f(v >> 16);
  }

  rs += __shfl_xor(rs, 32);
  ax += __shfl_xor(ax, 32);
  ay += __shfl_xor(ay, 32);

  if (half == 0) {
    float vx = ax / rs, vy = ay / rs;
    vx = vx > 0.f ? vx : __expf(vx) - 1.f;
    vy = vy > 0.f ? vy : __expf(vy) - 1.f;
    *(float2*)&out[(size_t)n * OUT_FEAT + 2 * c2] = make_float2(vx, vy);
  }
}

extern "C" void kernel_launch(void* const* d_in, const int* in_sizes, int n_in,
                              void* d_out, int out_size, void* d_ws, size_t ws_size,
                              hipStream_t stream) {
  const float* x = (const float*)d_in[0];  // (N, 128) fp32
  const float* W = (const float*)d_in[1];  // (128, 64) fp32
  const float* a = (const float*)d_in[2];  // (1, 128) fp32
  const int* edge = (const int*)d_in[3];   // (2, E) int32

  const int N = in_sizes[0] / IN_FEAT;
  const int E = in_sizes[3] / 2;
  const int* src = edge;
  const int* dst = edge + E;

  float* out = (float*)d_out;  // (N, 64) fp32

  // Workspace layout (~34 MB)
  char* p = (char*)d_ws;
  unsigned short* h = (unsigned short*)p; p += (size_t)N * OUT_FEAT * sizeof(unsigned short);
  float* s1 = (float*)p;      p += (size_t)N * sizeof(float);
  float* s2 = (float*)p;      p += (size_t)N * sizeof(float);
  int* counts = (int*)p;      p += (size_t)N * sizeof(int);
  int* row_start = (int*)p;   p += (size_t)N * sizeof(int);
  int* cursor = (int*)p;      p += (size_t)N * sizeof(int);
  int* bsums = (int*)p;       p += MAX_NBUK * sizeof(int);
  int* buk_cursor = (int*)p;  p += MAX_NBUK * sizeof(int);
  int* rec = (int*)p;         p += (size_t)E * sizeof(int);
  int2* bukdata = (int2*)p;   p += (size_t)E * sizeof(int2);

  const int NB = (N + 1023) / 1024;  // scan blocks == coarse buckets

  hipMemsetAsync(counts, 0, (size_t)N * sizeof(int), stream);

  int grid_gemm = (N + 63) / 64;
  gemm_mfma_kernel<<<grid_gemm, 256, 0, stream>>>(x, W, a, h, s1, s2, N);

  int grid_e = (E + 255) / 256;
  hist_kernel<<<grid_e, 256, 0, stream>>>(src, counts, E);
  scan_reduce_kernel<<<NB, 256, 0, stream>>>(counts, bsums, N);
  scan_bsums_kernel<<<1, 256, 0, stream>>>(bsums, buk_cursor, NB);
  scan_write_kernel<<<NB, 256, 0, stream>>>(counts, bsums, row_start, cursor, N);

  int grid_bin = (E + 256 * BIN_PER_THREAD - 1) / (256 * BIN_PER_THREAD);
  bin_kernel<<<grid_bin, 256, 0, stream>>>(src, dst, buk_cursor, bukdata, E);
  fine_scatter_kernel<<<grid_e, 256, 0, stream>>>(bukdata, cursor, rec, E);

  int grid_rows = (N * OUT_FEAT + 255) / 256;
  node_aggregate_kernel<<<grid_rows, 256, 0, stream>>>(rec, row_start, counts, h, s1, s2, out, N);
}

// Round 5
// 223.377 us; speedup vs baseline: 3.0342x; 1.3956x over previous
//
#include <hip/hip_runtime.h>

#define IN_FEAT 128
#define OUT_FEAT 64
#define LRELU_ALPHA 0.2f
#define BUK_SHIFT 9       // coarse bucket = src >> 9 (512 nodes/bucket)
#define BUK_SIZE 512
#define MAX_NBUK 256      // N <= 131072
#define BIN_PER_THREAD 16 // 4096 edges per bin block

typedef __attribute__((ext_vector_type(8))) short bf16x8;
typedef __attribute__((ext_vector_type(4))) float floatx4;

// fp32 -> bf16 bits, round-to-nearest-even (inputs are finite; no NaN guard)
__device__ __forceinline__ short f2bf(float f) {
  union { float f; unsigned u; } v; v.f = f;
  unsigned r = v.u + 0x7fff + ((v.u >> 16) & 1);
  return (short)(r >> 16);
}
__device__ __forceinline__ float bf2f(unsigned short s) {
  union { unsigned u; float f; } v; v.u = ((unsigned)s) << 16;
  return v.f;
}

// ---------------------------------------------------------------------------
// Kernel 1: h = bf16(x) @ bf16(W) via MFMA 16x16x32. Block = 4 waves = 64 rows.
// Fused: s1 = h@a1, s2 = h@a2 (quad shuffle reduction). h stored as bf16 bits.
// ---------------------------------------------------------------------------
__global__ __launch_bounds__(256) void gemm_mfma_kernel(
    const float* __restrict__ x, const float* __restrict__ W,
    const float* __restrict__ a, unsigned short* __restrict__ h,
    float* __restrict__ s1, float* __restrict__ s2, int N) {
  __shared__ __align__(16) short Wt[64 * 136];  // W^T bf16, stride 136
  __shared__ float a_sh[2 * OUT_FEAT];

  if (threadIdx.x < 2 * OUT_FEAT) a_sh[threadIdx.x] = a[threadIdx.x];
  for (int i = threadIdx.x; i < IN_FEAT * OUT_FEAT; i += 256) {
    int k = i >> 6, n = i & 63;
    Wt[n * 136 + k] = f2bf(W[i]);
  }
  __syncthreads();

  int wave = threadIdx.x >> 6;
  int lane = threadIdx.x & 63;
  int l = lane & 15;
  int quad = lane >> 4;

  int row_base = blockIdx.x * 64 + wave * 16;
  int m = row_base + l;
  int m_c = m < N ? m : N - 1;

  bf16x8 bfrag[4][4];
#pragma unroll
  for (int kt = 0; kt < 4; ++kt)
#pragma unroll
    for (int nt = 0; nt < 4; ++nt)
      bfrag[kt][nt] = *(const bf16x8*)&Wt[(nt * 16 + l) * 136 + kt * 32 + quad * 8];

  floatx4 acc[4] = {floatx4{0,0,0,0}, floatx4{0,0,0,0}, floatx4{0,0,0,0}, floatx4{0,0,0,0}};
  const float* xrow = x + (size_t)m_c * IN_FEAT;
#pragma unroll
  for (int kt = 0; kt < 4; ++kt) {
    float4 xa = *(const float4*)(xrow + kt * 32 + quad * 8);
    float4 xb = *(const float4*)(xrow + kt * 32 + quad * 8 + 4);
    bf16x8 af;
    af[0] = f2bf(xa.x); af[1] = f2bf(xa.y); af[2] = f2bf(xa.z); af[3] = f2bf(xa.w);
    af[4] = f2bf(xb.x); af[5] = f2bf(xb.y); af[6] = f2bf(xb.z); af[7] = f2bf(xb.w);
#pragma unroll
    for (int nt = 0; nt < 4; ++nt)
      acc[nt] = __builtin_amdgcn_mfma_f32_16x16x32_bf16(af, bfrag[kt][nt], acc[nt], 0, 0, 0);
  }

  int out_row = row_base + quad * 4;
#pragma unroll
  for (int reg = 0; reg < 4; ++reg) {
    int r = out_row + reg;
    if (r < N) {
#pragma unroll
      for (int nt = 0; nt < 4; ++nt)
        h[(size_t)r * OUT_FEAT + nt * 16 + l] = (unsigned short)f2bf(acc[nt][reg]);
    }
  }

  float p1[4] = {0, 0, 0, 0}, p2[4] = {0, 0, 0, 0};
#pragma unroll
  for (int nt = 0; nt < 4; ++nt) {
    float a1v = a_sh[nt * 16 + l];
    float a2v = a_sh[OUT_FEAT + nt * 16 + l];
#pragma unroll
    for (int reg = 0; reg < 4; ++reg) {
      p1[reg] += acc[nt][reg] * a1v;
      p2[reg] += acc[nt][reg] * a2v;
    }
  }
#pragma unroll
  for (int off = 1; off < 16; off <<= 1) {
#pragma unroll
    for (int reg = 0; reg < 4; ++reg) {
      p1[reg] += __shfl_xor(p1[reg], off);
      p2[reg] += __shfl_xor(p2[reg], off);
    }
  }
  if (l < 4) {
    int r = out_row + l;
    if (r < N) {
      float v1 = l == 0 ? p1[0] : (l == 1 ? p1[1] : (l == 2 ? p1[2] : p1[3]));
      float v2 = l == 0 ? p2[0] : (l == 1 ? p2[1] : (l == 2 ? p2[2] : p2[3]));
      s1[r] = v1;
      s2[r] = v2;
    }
  }
}

// ---------------------------------------------------------------------------
// Coarse histogram over 196 buckets: per-block LDS hist, <=196 global atomics
// per block onto a 784B array. No per-edge global atomics.
// ---------------------------------------------------------------------------
__global__ __launch_bounds__(256) void coarse_hist_kernel(
    const int* __restrict__ src, int* __restrict__ cbuk, int E) {
  __shared__ int lh[MAX_NBUK];
  int t = threadIdx.x;
  lh[t] = 0;
  __syncthreads();
  for (int e = blockIdx.x * 256 + t; e < E; e += gridDim.x * 256)
    atomicAdd(&lh[src[e] >> BUK_SHIFT], 1);
  __syncthreads();
  if (lh[t] > 0) atomicAdd(&cbuk[t], lh[t]);
}

// Exclusive scan of bucket counts -> buk_off (NB+1 entries) + bin cursors.
__global__ __launch_bounds__(256) void scan_buckets_kernel(
    const int* __restrict__ cbuk, int* __restrict__ buk_off,
    int* __restrict__ buk_cursor, int NB) {
  __shared__ int lds[MAX_NBUK];
  int t = threadIdx.x;
  if (t < NB) lds[t] = cbuk[t];
  __syncthreads();
  if (t == 0) {
    int run = 0;
    for (int i = 0; i < NB; ++i) { int v = lds[i]; lds[i] = run; run += v; }
    buk_off[NB] = run;  // == E
  }
  __syncthreads();
  if (t < NB) {
    buk_off[t] = lds[t];
    buk_cursor[t] = lds[t];
  }
}

// ---------------------------------------------------------------------------
// Phase 1: coarse bin by src>>9. Per-block LDS histogram + one global atomic
// per (block,bucket) reservation -> ~167B contiguous write runs per bucket.
// ---------------------------------------------------------------------------
__global__ __launch_bounds__(256) void bin_kernel(
    const int* __restrict__ src, const int* __restrict__ dst,
    int* __restrict__ buk_cursor, int2* __restrict__ bukdata, int E) {
  __shared__ int lhist[MAX_NBUK];
  __shared__ int lbase[MAX_NBUK];
  int t = threadIdx.x;
  lhist[t] = 0;
  __syncthreads();

  int base_e = blockIdx.x * (256 * BIN_PER_THREAD);
  int s[BIN_PER_THREAD], d[BIN_PER_THREAD];
#pragma unroll
  for (int j = 0; j < BIN_PER_THREAD; ++j) {
    int e = base_e + j * 256 + t;
    bool valid = e < E;
    s[j] = valid ? src[e] : 0;
    d[j] = valid ? dst[e] : 0;
    if (valid) atomicAdd(&lhist[s[j] >> BUK_SHIFT], 1);
  }
  __syncthreads();
  {
    int c = lhist[t];
    lbase[t] = c > 0 ? atomicAdd(&buk_cursor[t], c) : 0;
    lhist[t] = 0;  // reuse as in-block cursor
  }
  __syncthreads();
#pragma unroll
  for (int j = 0; j < BIN_PER_THREAD; ++j) {
    int e = base_e + j * 256 + t;
    if (e < E) {
      int b = s[j] >> BUK_SHIFT;
      int pos = lbase[b] + atomicAdd(&lhist[b], 1);
      bukdata[pos] = make_int2(s[j], d[j]);
    }
  }
}

// ---------------------------------------------------------------------------
// Phase 2: one block per bucket (512 nodes, ~8200 edges). LDS fine histogram
// + LDS block-scan -> coalesced row_start/counts writes; LDS-cursor scatter of
// rec confined to a ~32KB window (L2-resident, lines merge). No global
// cursor array, no per-edge global atomics.
// ---------------------------------------------------------------------------
__global__ __launch_bounds__(256) void bucket_build_kernel(
    const int2* __restrict__ bukdata, const int* __restrict__ buk_off,
    int* __restrict__ row_start, int* __restrict__ counts,
    int* __restrict__ rec, int N) {
  __shared__ int lhist[BUK_SIZE];
  __shared__ int lcur[BUK_SIZE];
  __shared__ int wtot[4];
  int t = threadIdx.x;
  int buk = blockIdx.x;
  int beg = buk_off[buk];
  int end = buk_off[buk + 1];

  lhist[t] = 0;
  lhist[t + 256] = 0;
  __syncthreads();
  for (int i = beg + t; i < end; i += 256)
    atomicAdd(&lhist[bukdata[i].x & (BUK_SIZE - 1)], 1);
  __syncthreads();

  // Block-wide exclusive scan over 512 counters; thread owns 2t, 2t+1.
  int v0 = lhist[2 * t], v1 = lhist[2 * t + 1];
  int ts = v0 + v1;
  int lane = t & 63, w = t >> 6;
  int xs = ts;
#pragma unroll
  for (int off = 1; off < 64; off <<= 1) {
    int y = __shfl_up(xs, off);
    if (lane >= off) xs += y;
  }
  if (lane == 63) wtot[w] = xs;
  __syncthreads();
  int woff = 0;
  for (int i = 0; i < w; ++i) woff += wtot[i];
  int excl = woff + (xs - ts);

  int node = (buk << BUK_SHIFT) + 2 * t;
  if (node < N)     { row_start[node] = beg + excl;       counts[node] = v0; }
  if (node + 1 < N) { row_start[node + 1] = beg + excl + v0; counts[node + 1] = v1; }
  lcur[2 * t] = excl;
  lcur[2 * t + 1] = excl + v0;
  __syncthreads();

  for (int i = beg + t; i < end; i += 256) {
    int2 p = bukdata[i];
    int pos = beg + atomicAdd(&lcur[p.x & (BUK_SIZE - 1)], 1);
    rec[pos] = p.y;
  }
}

// ---------------------------------------------------------------------------
// Kernel 3: atomic-free aggregate. One wave per node; bf16 h row = 128B =
// 32 lanes x ushort2; the two wave-halves process alternating edges
// (8 gathers in flight with the x4 unroll). Cross-half shfl_xor(32) reduce.
// Fused finalize: out = elu(acc / rowsum).
// ---------------------------------------------------------------------------
__global__ __launch_bounds__(256) void node_aggregate_kernel(
    const int* __restrict__ rec, const int* __restrict__ row_start,
    const int* __restrict__ counts, const unsigned short* __restrict__ h,
    const float* __restrict__ s1, const float* __restrict__ s2,
    float* __restrict__ out, int N) {
  int tid = blockIdx.x * 256 + threadIdx.x;
  int n = tid >> 6;
  if (n >= N) return;
  int lane = threadIdx.x & 63;
  int half = lane >> 5;
  int c2 = lane & 31;

  int start = row_start[n];
  int cnt = counts[n];
  float s1n = s1[n];
  float ax = 0.f, ay = 0.f, rs = 0.f;

  int i = 0;
  for (; i + 8 <= cnt; i += 8) {
    int b0 = start + i + half;
    int d0 = rec[b0], d1 = rec[b0 + 2], d2 = rec[b0 + 4], d3 = rec[b0 + 6];
    float t0 = s2[d0], t1 = s2[d1], t2 = s2[d2], t3 = s2[d3];
    unsigned v0 = *(const unsigned*)&h[(size_t)d0 * OUT_FEAT + 2 * c2];
    unsigned v1 = *(const unsigned*)&h[(size_t)d1 * OUT_FEAT + 2 * c2];
    unsigned v2 = *(const unsigned*)&h[(size_t)d2 * OUT_FEAT + 2 * c2];
    unsigned v3 = *(const unsigned*)&h[(size_t)d3 * OUT_FEAT + 2 * c2];
    float sc0 = s1n + t0, sc1 = s1n + t1, sc2 = s1n + t2, sc3 = s1n + t3;
    float e0 = __expf(-(sc0 > 0.f ? sc0 : LRELU_ALPHA * sc0));
    float e1 = __expf(-(sc1 > 0.f ? sc1 : LRELU_ALPHA * sc1));
    float e2 = __expf(-(sc2 > 0.f ? sc2 : LRELU_ALPHA * sc2));
    float e3 = __expf(-(sc3 > 0.f ? sc3 : LRELU_ALPHA * sc3));
    rs += (e0 + e1) + (e2 + e3);
    ax += e0 * bf2f(v0 & 0xffff) + e1 * bf2f(v1 & 0xffff) +
          e2 * bf2f(v2 & 0xffff) + e3 * bf2f(v3 & 0xffff);
    ay += e0 * bf2f(v0 >> 16) + e1 * bf2f(v1 >> 16) +
          e2 * bf2f(v2 >> 16) + e3 * bf2f(v3 >> 16);
  }
  for (; i + 2 <= cnt; i += 2) {
    int d = rec[start + i + half];
    float sc = s1n + s2[d];
    unsigned v = *(const unsigned*)&h[(size_t)d * OUT_FEAT + 2 * c2];
    float ee = __expf(-(sc > 0.f ? sc : LRELU_ALPHA * sc));
    rs += ee;
    ax += ee * bf2f(v & 0xffff);
    ay += ee * bf2f(v >> 16);
  }
  if (i < cnt && half == 0) {
    int d = rec[start + i];
    float sc = s1n + s2[d];
    unsigned v = *(const unsigned*)&h[(size_t)d * OUT_FEAT + 2 * c2];
    float ee = __expf(-(sc > 0.f ? sc : LRELU_ALPHA * sc));
    rs += ee;
    ax += ee * bf2f(v & 0xffff);
    ay += ee * bf2f(v >> 16);
  }

  rs += __shfl_xor(rs, 32);
  ax += __shfl_xor(ax, 32);
  ay += __shfl_xor(ay, 32);

  if (half == 0) {
    float vx = ax / rs, vy = ay / rs;
    vx = vx > 0.f ? vx : __expf(vx) - 1.f;
    vy = vy > 0.f ? vy : __expf(vy) - 1.f;
    *(float2*)&out[(size_t)n * OUT_FEAT + 2 * c2] = make_float2(vx, vy);
  }
}

extern "C" void kernel_launch(void* const* d_in, const int* in_sizes, int n_in,
                              void* d_out, int out_size, void* d_ws, size_t ws_size,
                              hipStream_t stream) {
  const float* x = (const float*)d_in[0];  // (N, 128) fp32
  const float* W = (const float*)d_in[1];  // (128, 64) fp32
  const float* a = (const float*)d_in[2];  // (1, 128) fp32
  const int* edge = (const int*)d_in[3];   // (2, E) int32

  const int N = in_sizes[0] / IN_FEAT;
  const int E = in_sizes[3] / 2;
  const int* src = edge;
  const int* dst = edge + E;

  float* out = (float*)d_out;  // (N, 64) fp32

  // Workspace layout (~33 MB)
  char* p = (char*)d_ws;
  unsigned short* h = (unsigned short*)p; p += (size_t)N * OUT_FEAT * sizeof(unsigned short);
  float* s1 = (float*)p;      p += (size_t)N * sizeof(float);
  float* s2 = (float*)p;      p += (size_t)N * sizeof(float);
  int* counts = (int*)p;      p += (size_t)N * sizeof(int);
  int* row_start = (int*)p;   p += (size_t)N * sizeof(int);
  int* cbuk = (int*)p;        p += MAX_NBUK * sizeof(int);
  int* buk_off = (int*)p;     p += (MAX_NBUK + 1) * sizeof(int);
  int* buk_cursor = (int*)p;  p += MAX_NBUK * sizeof(int);
  int* rec = (int*)p;         p += (size_t)E * sizeof(int);
  int2* bukdata = (int2*)p;   p += (size_t)E * sizeof(int2);

  const int NB = (N + BUK_SIZE - 1) / BUK_SIZE;  // coarse buckets (196)

  hipMemsetAsync(cbuk, 0, MAX_NBUK * sizeof(int), stream);

  int grid_gemm = (N + 63) / 64;
  gemm_mfma_kernel<<<grid_gemm, 256, 0, stream>>>(x, W, a, h, s1, s2, N);

  coarse_hist_kernel<<<512, 256, 0, stream>>>(src, cbuk, E);
  scan_buckets_kernel<<<1, 256, 0, stream>>>(cbuk, buk_off, buk_cursor, NB);

  int grid_bin = (E + 256 * BIN_PER_THREAD - 1) / (256 * BIN_PER_THREAD);
  bin_kernel<<<grid_bin, 256, 0, stream>>>(src, dst, buk_cursor, bukdata, E);
  bucket_build_kernel<<<NB, 256, 0, stream>>>(bukdata, buk_off, row_start, counts, rec, N);

  int grid_rows = (N * OUT_FEAT + 255) / 256;
  node_aggregate_kernel<<<grid_rows, 256, 0, stream>>>(rec, row_start, counts, h, s1, s2, out, N);
}